// Round 3
// baseline (229.762 us; speedup 1.0000x reference)
//
#include <hip/hip_runtime.h>
#include <math.h>

#define D_MODEL 512
#define STATE_DIM 16
#define MASK_BUCKETS 2048

typedef float v4f __attribute__((ext_vector_type(4)));

__device__ __forceinline__ v4f f4_load(const float* p) {
    return *(const v4f*)p;
}
__device__ __forceinline__ v4f f4_fma(float s, v4f a, v4f b) {
    return (v4f){fmaf(s, a.x, b.x), fmaf(s, a.y, b.y), fmaf(s, a.z, b.z), fmaf(s, a.w, b.w)};
}

// Main kernel: each block owns a contiguous chunk of points (chunk % N == 0
// guaranteed by launch config so one batch index b per block).
// Thread layout: d4 = tid & 127 -> float4 slice of D=512; sub = tid >> 7 ->
// which of 2 points per iteration. Wave = 64 lanes * 16B = 1KB contiguous
// per point for both the mask_embed gather and the output store.
__global__ __launch_bounds__(256) void point_proj_kernel(
    const float* __restrict__ xyz,
    const float* __restrict__ state,
    const float* __restrict__ rgb,
    const int*   __restrict__ mask_id,
    const float* __restrict__ Wxyz,
    const float* __restrict__ Wrgb,
    const float* __restrict__ rgb_alpha,
    const float* __restrict__ Wg,
    const float* __restrict__ gripper_alpha,
    const float* __restrict__ mask_embed,
    float* __restrict__ out,
    int points_per_block,
    int n_points)  // N (per batch)
{
    const int tid = threadIdx.x;
    const int d   = (tid & 127) << 2;   // float4 column slice
    const int sub = tid >> 7;           // 0 or 1: which point this iter

    const float ra = rgb_alpha[0];
    const float ga = gripper_alpha[0];

    const long long p0 = (long long)blockIdx.x * points_per_block;
    const int b = (int)(p0 / n_points);  // constant for the whole block

    // gripper xyz for this batch (broadcast loads, L1-served)
    const float gx = state[b * STATE_DIM + 0];
    const float gy = state[b * STATE_DIM + 1];
    const float gz = state[b * STATE_DIM + 2];

    // --- fold weights into registers (done once per block) ---
    v4f G0 = f4_load(&Wg[0 * D_MODEL + d]);
    v4f G1 = f4_load(&Wg[1 * D_MODEL + d]);
    v4f G2 = f4_load(&Wg[2 * D_MODEL + d]);
    v4f G3 = f4_load(&Wg[3 * D_MODEL + d]);
    G0 *= ga; G1 *= ga; G2 *= ga; G3 *= ga;

    // per-batch constant: -ga * (gxyz . Wg[0:3])
    v4f Cb = -(G0 * gx + G1 * gy + G2 * gz);

    // A_k = Wxyz[k] + ga*Wg[k]  (since rel = xyz - gxyz, xyz part folds in)
    v4f A0 = f4_load(&Wxyz[0 * D_MODEL + d]) + G0;
    v4f A1 = f4_load(&Wxyz[1 * D_MODEL + d]) + G1;
    v4f A2 = f4_load(&Wxyz[2 * D_MODEL + d]) + G2;

    v4f R0 = f4_load(&Wrgb[0 * D_MODEL + d]);
    v4f R1 = f4_load(&Wrgb[1 * D_MODEL + d]);
    v4f R2 = f4_load(&Wrgb[2 * D_MODEL + d]);
    R0 *= ra; R1 *= ra; R2 *= ra;

    const int iters = points_per_block >> 1;  // 2 points per iteration
    for (int i = 0; i < iters; ++i) {
        const long long p = p0 + (long long)(i << 1) + sub;

        // per-point scalars (same address across wave -> broadcast)
        const float x  = xyz[p * 3 + 0];
        const float y  = xyz[p * 3 + 1];
        const float z  = xyz[p * 3 + 2];
        const float r0 = rgb[p * 3 + 0];
        const float r1 = rgb[p * 3 + 1];
        const float r2 = rgb[p * 3 + 2];
        const int   m  = mask_id[p] & (MASK_BUCKETS - 1);

        const float rx = x - gx, ry = y - gy, rz = z - gz;
        const float dist = sqrtf(rx * rx + ry * ry + rz * rz);

        // coalesced 1KB/wave gather from 4MB table (L2/L3-resident)
        v4f me = f4_load(&mask_embed[(size_t)m * D_MODEL + d]);

        v4f o = Cb + me;
        o = f4_fma(x,    A0, o);
        o = f4_fma(y,    A1, o);
        o = f4_fma(z,    A2, o);
        o = f4_fma(r0,   R0, o);
        o = f4_fma(r1,   R1, o);
        o = f4_fma(r2,   R2, o);
        o = f4_fma(dist, G3, o);

        // nontemporal: don't let the 1GB write stream evict mask_embed from L2
        __builtin_nontemporal_store(o, (v4f*)&out[(size_t)p * D_MODEL + d]);
    }
}

// state token: st = silu(state @ Ws1 + bs1) @ Ws2 + bs2, B blocks of 512 thr
__global__ __launch_bounds__(512) void state_token_kernel(
    const float* __restrict__ state,
    const float* __restrict__ Ws1,
    const float* __restrict__ bs1,
    const float* __restrict__ Ws2,
    const float* __restrict__ bs2,
    float* __restrict__ out)  // already offset to state_token base
{
    __shared__ float u[D_MODEL];
    const int b = blockIdx.x;
    const int d = threadIdx.x;

    float acc = bs1[d];
#pragma unroll
    for (int k = 0; k < STATE_DIM; ++k)
        acc = fmaf(state[b * STATE_DIM + k], Ws1[k * D_MODEL + d], acc);
    // silu
    u[d] = acc / (1.0f + expf(-acc));
    __syncthreads();

    float acc2 = bs2[d];
#pragma unroll 8
    for (int k = 0; k < D_MODEL; ++k)
        acc2 = fmaf(u[k], Ws2[k * D_MODEL + d], acc2);

    out[(size_t)b * D_MODEL + d] = acc2;
}

extern "C" void kernel_launch(void* const* d_in, const int* in_sizes, int n_in,
                              void* d_out, int out_size, void* d_ws, size_t ws_size,
                              hipStream_t stream) {
    const float* xyz           = (const float*)d_in[0];
    const float* state         = (const float*)d_in[1];
    const float* rgb           = (const float*)d_in[2];
    const int*   mask_id       = (const int*)  d_in[3];
    const float* Wxyz          = (const float*)d_in[4];
    const float* Wrgb          = (const float*)d_in[5];
    const float* rgb_alpha     = (const float*)d_in[6];
    const float* Wg            = (const float*)d_in[7];
    const float* gripper_alpha = (const float*)d_in[8];
    const float* Ws1           = (const float*)d_in[9];
    const float* bs1           = (const float*)d_in[10];
    const float* Ws2           = (const float*)d_in[11];
    const float* bs2           = (const float*)d_in[12];
    const float* mask_embed    = (const float*)d_in[13];
    float* out = (float*)d_out;

    const int B = in_sizes[1] / STATE_DIM;              // 8
    const long long total_points = in_sizes[3];         // B*N = 524288
    const int N = (int)(total_points / B);              // 65536

    // 256 points per block: divides N, so each block sees exactly one b.
    const int ppb = 256;
    const int grid = (int)(total_points / ppb);         // 2048 blocks

    point_proj_kernel<<<grid, 256, 0, stream>>>(
        xyz, state, rgb, mask_id, Wxyz, Wrgb, rgb_alpha, Wg, gripper_alpha,
        mask_embed, out, ppb, N);

    state_token_kernel<<<B, D_MODEL, 0, stream>>>(
        state, Ws1, bs1, Ws2, bs2,
        out + (size_t)total_points * D_MODEL);
}